// Round 5
// baseline (928.929 us; speedup 1.0000x reference)
//
#include <hip/hip_runtime.h>

typedef __bf16 bf16x8 __attribute__((ext_vector_type(8)));
typedef float f32x4 __attribute__((ext_vector_type(4)));
typedef unsigned short ushortT;

__device__ __forceinline__ unsigned short f2bf(float f) {
    unsigned u = __float_as_uint(f);
    u += 0x7fffu + ((u >> 16) & 1u);
    return (unsigned short)(u >> 16);
}
__device__ __forceinline__ float bf2f(unsigned short h) {
    return __uint_as_float((unsigned)h << 16);
}

// ---------------- conv1 weight prep: (7,64,1,7,7,7) f32 -> bf16 [co][3136] ----------------
// k = (kt*7+kd)*64 + kh*8 + kw, kh/kw padded to 8 (pad slots = 0).
__global__ void wprep1(const float* __restrict__ w, ushortT* __restrict__ out) {
    int idx = blockIdx.x * 256 + threadIdx.x; // 64*3136 = 200704
    if (idx >= 200704) return;
    int k = idx % 3136, co = idx / 3136;
    int kw = k & 7, kh = (k >> 3) & 7, kdt = k >> 6;
    int kt = kdt / 7, kd = kdt % 7;
    float v = 0.f;
    if (kh < 7 && kw < 7)
        v = w[(size_t)(kt * 64 + co) * 343 + kd * 49 + kh * 7 + kw];
    out[idx] = f2bf(v);
}

// ---------------- conv1 v3: MFMA implicit im2col, out bf16 [18^4][64], fused relu ----------
// block = 128 pos (tile 1x4x4x8), 4 waves; wave = 32 pos x 64 co (m=2, c=4).
// LDS x tile: [lt 7][ld 13][lh 14][lw 22] bf16 (row stride 22 sh = 11 dwords, odd -> no bank
// conflicts). A (weights) from global (L2/L1-resident, shared across the 4 waves).
__global__ __launch_bounds__(256) void conv1_mfma3(const float* __restrict__ x,
                                                   const ushortT* __restrict__ aw,
                                                   ushortT* __restrict__ out) {
    __shared__ ushortT xs[28028]; // 56,056 B

    int bid = blockIdx.x;
    int wt = bid % 3; int r = bid / 3;
    int ht = r % 5; r /= 5;
    int dt = r % 5; int ot = r / 5; // grid = 3*5*5*18 = 1350
    int od0 = dt * 4, oh0 = ht * 4, ow0 = wt * 8;
    int it0 = 2 * ot - 3, id0 = 2 * od0 - 3, ih0 = 2 * oh0 - 3, iw0 = 2 * ow0 - 3;

    int tid = threadIdx.x;
    // ---- stage x tile (bf16, zero halo) ----
    {
        int lh = tid >> 4, lw2 = tid & 15;
        bool act = (lh < 14) && (lw2 < 11);
        int gh = ih0 + lh;
        int gw0 = iw0 + 2 * lw2, gw1 = gw0 + 1;
        bool hok = (unsigned)gh < 36u;
        bool w0ok = (unsigned)gw0 < 36u, w1ok = (unsigned)gw1 < 36u;
        for (int lt = 0; lt < 7; ++lt) {
            int gt = it0 + lt;
            bool tok = (unsigned)gt < 36u;
            int rb0 = (lt * 13) * 14;
            for (int ld = 0; ld < 13; ++ld) {
                int gd = id0 + ld;
                bool ok = act && tok && ((unsigned)gd < 36u) && hok;
                const float* xr = x + ((long)(gt * 36 + gd) * 36 + gh) * 36;
                float f0 = (ok && w0ok) ? xr[gw0] : 0.f;
                float f1 = (ok && w1ok) ? xr[gw1] : 0.f;
                if (act) {
                    unsigned pack = (unsigned)f2bf(f0) | ((unsigned)f2bf(f1) << 16);
                    *(unsigned*)(xs + ((rb0 + ld * 14) + lh) * 22 + 2 * lw2) = pack;
                }
            }
        }
    }
    __syncthreads();

    int lane = tid & 63, wv = tid >> 6;
    int l15 = lane & 15, g = lane >> 4;
    int ph = l15 >> 2, pwl = l15 & 3;
    int pdh = wv >> 1;        // pd half: pd = pdh*2 + m
    int pwb = (wv & 1) * 4;   // pw base: pw = pwb + pwl

    const ushortT* a_base = aw + (size_t)l15 * 3136 + g * 8;
    int laneoff = (2 * ph + g) * 22 + 2 * pwb + 2 * pwl;

    f32x4 acc[4][2];
#pragma unroll
    for (int c = 0; c < 4; ++c)
#pragma unroll
        for (int m = 0; m < 2; ++m) acc[c][m] = (f32x4){0.f, 0.f, 0.f, 0.f};

    int ka = 0;
    for (int kt = 0; kt < 7; ++kt) {
        for (int kd = 0; kd < 7; ++kd) {
            int rowbase = (kt * 13 + 4 * pdh + kd) * 308 + laneoff;
#pragma unroll
            for (int khq = 0; khq < 2; ++khq) {
                bf16x8 av0 = *(const bf16x8*)(a_base + ka);
                bf16x8 av1 = *(const bf16x8*)(a_base + 50176 + ka);
                bf16x8 av2 = *(const bf16x8*)(a_base + 100352 + ka);
                bf16x8 av3 = *(const bf16x8*)(a_base + 150528 + ka);
                ka += 32;
                int fb = rowbase + khq * 88;
#pragma unroll
                for (int m = 0; m < 2; ++m) {
                    int off = fb + m * 616;
                    union { unsigned u[4]; bf16x8 v; } bb;
                    bb.u[0] = *(const unsigned*)(xs + off);
                    bb.u[1] = *(const unsigned*)(xs + off + 2);
                    bb.u[2] = *(const unsigned*)(xs + off + 4);
                    bb.u[3] = *(const unsigned*)(xs + off + 6);
                    acc[0][m] = __builtin_amdgcn_mfma_f32_16x16x32_bf16(av0, bb.v, acc[0][m], 0, 0, 0);
                    acc[1][m] = __builtin_amdgcn_mfma_f32_16x16x32_bf16(av1, bb.v, acc[1][m], 0, 0, 0);
                    acc[2][m] = __builtin_amdgcn_mfma_f32_16x16x32_bf16(av2, bb.v, acc[2][m], 0, 0, 0);
                    acc[3][m] = __builtin_amdgcn_mfma_f32_16x16x32_bf16(av3, bb.v, acc[3][m], 0, 0, 0);
                }
            }
        }
    }

    // C: col l15 -> (ph, pwl); row = g*4 + reg (+ c*16)
    int oh = oh0 + ph;
    if (oh < 18) {
#pragma unroll
        for (int m = 0; m < 2; ++m) {
            int od = od0 + pdh * 2 + m;
            int ow = ow0 + pwb + pwl;
            if (od < 18 && ow < 18) {
                int pos = ((ot * 18 + od) * 18 + oh) * 18 + ow;
#pragma unroll
                for (int c = 0; c < 4; ++c) {
                    ushort4 st;
                    st.x = f2bf(fmaxf(acc[c][m][0], 0.f));
                    st.y = f2bf(fmaxf(acc[c][m][1], 0.f));
                    st.z = f2bf(fmaxf(acc[c][m][2], 0.f));
                    st.w = f2bf(fmaxf(acc[c][m][3], 0.f));
                    *(ushort4*)(out + (size_t)pos * 64 + c * 16 + g * 4) = st;
                }
            }
        }
    }
}

// ---------------- maxpool 3^4 s2 p1: bf16 [18^4][64] -> bf16 [9^4][64]; zero-fills zb ------
// post-ReLU values are >= 0 so bf16 compares as unsigned short.
__global__ void maxpool2(const ushortT* __restrict__ in, ushortT* __restrict__ out,
                         ushortT* __restrict__ zb) {
    int idx = blockIdx.x * 256 + threadIdx.x;
    if (idx < 128) zb[idx] = 0;
    if (idx >= 6561 * 16) return;
    int c4 = idx & 15;
    int p = idx >> 4;
    int ow = p % 9; int t = p / 9;
    int oh = t % 9; t /= 9;
    int od = t % 9; int ot = t / 9;
    ushort4 m = {0, 0, 0, 0};
    for (int kt = 0; kt < 3; ++kt) { int it = 2 * ot + kt - 1; if ((unsigned)it >= 18u) continue;
        for (int kd = 0; kd < 3; ++kd) { int id = 2 * od + kd - 1; if ((unsigned)id >= 18u) continue;
            for (int kh = 0; kh < 3; ++kh) { int ih = 2 * oh + kh - 1; if ((unsigned)ih >= 18u) continue;
                int rb = ((it * 18 + id) * 18 + ih) * 18;
                for (int kw = 0; kw < 3; ++kw) { int iw = 2 * ow + kw - 1; if ((unsigned)iw >= 18u) continue;
                    ushort4 v = *(const ushort4*)(in + (size_t)(rb + iw) * 64 + c4 * 4);
                    m.x = v.x > m.x ? v.x : m.x;
                    m.y = v.y > m.y ? v.y : m.y;
                    m.z = v.z > m.z ? v.z : m.z;
                    m.w = v.w > m.w ? v.w : m.w;
                }
            }
        }
    }
    *(ushort4*)(out + (size_t)p * 64 + c4 * 4) = m;
}

// ---------------- weight prep: w f32 [3][Co][Ci][27] -> bf16 [(i*27+tap)][Co][Ci] ----------
__global__ void wprep(const float* __restrict__ w, ushortT* __restrict__ out, int Ci, int Co) {
    __shared__ float tile[13824]; // up to 512*27
    int i = blockIdx.x / Co, co = blockIdx.x % Co;
    const float* src = w + (size_t)(i * Co + co) * Ci * 27;
    int n = Ci * 27;
    for (int t = threadIdx.x; t < n; t += 256) tile[t] = src[t]; // tile[ci*27+tap]
    __syncthreads();
    for (int t = threadIdx.x; t < n; t += 256) {
        int tap = t / Ci, ci = t % Ci;
        out[((size_t)(i * 27 + tap) * Co + co) * Ci + ci] = f2bf(tile[ci * 27 + tap]);
    }
}

// ---------------- MFMA implicit-GEMM residual conv ----------------
template <int KC, int FUSE>
__global__ void convmfma(const ushortT* __restrict__ xb, const ushortT* __restrict__ wt,
                         const float* __restrict__ bias, const ushortT* __restrict__ res,
                         ushortT* __restrict__ outb, float* __restrict__ part,
                         const ushortT* __restrict__ zq,
                         int Ci, int Co, int T, int O, int stride, int chunk) {
    int lane = threadIdx.x & 63;
    int wv = threadIdx.x >> 6;
    int p0 = blockIdx.x * 16;
    int co0 = (blockIdx.y * 4 + wv) * 16;
    int cbase = blockIdx.z * chunk;

    int pn = p0 + (lane & 15);
    int O2 = O * O, O3 = O2 * O, O4 = O3 * O;
    bool pv = pn < O4;
    int pc = pv ? pn : 0;
    int ow = pc % O, oh = (pc / O) % O, od = (pc / O2) % O, ot = pc / O3;
    int g = lane >> 4;
    int kl = cbase + g * 8;

    const ushortT* aRow = wt + (size_t)(co0 + (lane & 15)) * Ci + kl;
    size_t tapStride = (size_t)Co * Ci;
    const ushortT* zp = zq + g * 8;

    f32x4 acc = {0.f, 0.f, 0.f, 0.f};

    int itb = ot * stride - 1, idb = od * stride - 1, ihb = oh * stride - 1, iwb = ow * stride - 1;

    for (int i = 0; i < 3; ++i) {
        int it = itb + i;
        bool vt = pv && ((unsigned)it < (unsigned)T);
        for (int kd = 0; kd < 3; ++kd) {
            int id = idb + kd;
            bool vdd = vt && ((unsigned)id < (unsigned)T);
            int btd = (it * T + id) * T;
            for (int kh = 0; kh < 3; ++kh) {
                int ih = ihb + kh;
                bool vh = vdd && ((unsigned)ih < (unsigned)T);
                for (int kw = 0; kw < 3; ++kw) {
                    int iw = iwb + kw;
                    bool v = vh && ((unsigned)iw < (unsigned)T);
                    int ip = (btd + ih) * T + iw;
                    const ushortT* bp = v ? (xb + (size_t)ip * Ci + kl) : zp;
                    int tapIdx = (i * 9 + kd * 3 + kh) * 3 + kw;
                    const ushortT* apw = aRow + (size_t)tapIdx * tapStride;
#pragma unroll
                    for (int kc = 0; kc < KC; ++kc) {
                        bf16x8 av = *(const bf16x8*)(apw + kc * 32);
                        bf16x8 bv = *(const bf16x8*)(bp + kc * 32);
                        acc = __builtin_amdgcn_mfma_f32_16x16x32_bf16(av, bv, acc, 0, 0, 0);
                    }
                }
            }
        }
    }

    if (!pv) return;
    int cob = co0 + g * 4;
    if (FUSE) {
        float bb[4] = {0.f, 0.f, 0.f, 0.f};
        for (int i = 0; i < 3; ++i) {
            int it = itb + i;
            if ((unsigned)it < (unsigned)T) {
#pragma unroll
                for (int r = 0; r < 4; ++r) bb[r] += bias[i * Co + cob + r];
            }
        }
        float rv[4] = {0.f, 0.f, 0.f, 0.f};
        if (res) {
            ushort4 rr = *(const ushort4*)(res + (size_t)pn * Co + cob);
            rv[0] = bf2f(rr.x); rv[1] = bf2f(rr.y); rv[2] = bf2f(rr.z); rv[3] = bf2f(rr.w);
        }
        ushort4 st;
        st.x = f2bf(fmaxf(acc[0] + bb[0] + rv[0], 0.f));
        st.y = f2bf(fmaxf(acc[1] + bb[1] + rv[1], 0.f));
        st.z = f2bf(fmaxf(acc[2] + bb[2] + rv[2], 0.f));
        st.w = f2bf(fmaxf(acc[3] + bb[3] + rv[3], 0.f));
        *(ushort4*)(outb + (size_t)pn * Co + cob) = st;
    } else {
        *(f32x4*)(part + ((size_t)blockIdx.z * O4 + pn) * Co + cob) = acc;
    }
}

// ---------------- finalize for k-split convs ----------------
__global__ void finalize_k(const float* __restrict__ part, int KS,
                           const float* __restrict__ bias, const ushortT* __restrict__ res,
                           ushortT* __restrict__ outb, int Co, int O4, int T, int O, int stride,
                           int total) {
    int idx = blockIdx.x * 256 + threadIdx.x;
    if (idx >= total) return;
    int co = idx % Co;
    int pos = idx / Co;
    float v = 0.f;
    for (int z = 0; z < KS; ++z) v += part[((size_t)z * O4 + pos) * Co + co];
    int ot = pos / (O * O * O);
    for (int i = 0; i < 3; ++i) {
        int it = ot * stride + i - 1;
        if ((unsigned)it < (unsigned)T) v += bias[i * Co + co];
    }
    if (res) v += bf2f(res[idx]);
    outb[idx] = f2bf(fmaxf(v, 0.f));
}

// ---------------- downsample 1x1 conv stride2 (vectorized ci) ----------------
__global__ void dwconv2(const ushortT* __restrict__ x, const float* __restrict__ w,
                        ushortT* __restrict__ out, int Ci, int Co, int T, int O, int total) {
    int idx = blockIdx.x * 256 + threadIdx.x;
    if (idx >= total) return;
    int co = idx % Co;
    int pos = idx / Co;
    int O2 = O * O, O3 = O2 * O;
    int ow = pos % O, oh = (pos / O) % O, od = (pos / O2) % O, ot = pos / O3;
    int ip = (((2 * ot) * T + 2 * od) * T + 2 * oh) * T + 2 * ow;
    const ushortT* xp = x + (size_t)ip * Ci;
    const float* wp = w + (size_t)co * Ci;
    float acc = 0.f;
    for (int c8 = 0; c8 < Ci; c8 += 8) {
        uint4 xv = *(const uint4*)(xp + c8);
        float4 w0 = *(const float4*)(wp + c8);
        float4 w1 = *(const float4*)(wp + c8 + 4);
        acc = fmaf(bf2f((unsigned short)(xv.x & 0xffff)), w0.x, acc);
        acc = fmaf(bf2f((unsigned short)(xv.x >> 16)),    w0.y, acc);
        acc = fmaf(bf2f((unsigned short)(xv.y & 0xffff)), w0.z, acc);
        acc = fmaf(bf2f((unsigned short)(xv.y >> 16)),    w0.w, acc);
        acc = fmaf(bf2f((unsigned short)(xv.z & 0xffff)), w1.x, acc);
        acc = fmaf(bf2f((unsigned short)(xv.z >> 16)),    w1.y, acc);
        acc = fmaf(bf2f((unsigned short)(xv.w & 0xffff)), w1.z, acc);
        acc = fmaf(bf2f((unsigned short)(xv.w >> 16)),    w1.w, acc);
    }
    out[idx] = f2bf(acc);
}

// ---------------- avgpool 2^4 + FC (512 -> 1) ----------------
__global__ void avgfc2(const ushortT* __restrict__ xin, const float* __restrict__ fw,
                       const float* __restrict__ fb, float* __restrict__ out) {
    __shared__ float ls[8];
    int t = threadIdx.x; // 512
    float s = 0.f;
#pragma unroll
    for (int pp = 0; pp < 16; ++pp) s += bf2f(xin[pp * 512 + t]);
    s = s * (1.f / 16.f) * fw[t];
    for (int off = 32; off > 0; off >>= 1) s += __shfl_xor(s, off, 64);
    if ((t & 63) == 0) ls[t >> 6] = s;
    __syncthreads();
    if (t == 0) {
        float tot = 0.f;
#pragma unroll
        for (int i = 0; i < 8; ++i) tot += ls[i];
        out[0] = tot + fb[0];
    }
}

extern "C" void kernel_launch(void* const* d_in, const int* in_sizes, int n_in,
                              void* d_out, int out_size, void* d_ws, size_t ws_size,
                              hipStream_t stream) {
    const float* x       = (const float*)d_in[0];
    const float* conv1_w = (const float*)d_in[1];
    const float* l1_w1 = (const float*)d_in[2];
    const float* l1_b1 = (const float*)d_in[3];
    const float* l1_w2 = (const float*)d_in[4];
    const float* l1_b2 = (const float*)d_in[5];
    const float* l2_w1 = (const float*)d_in[6];
    const float* l2_b1 = (const float*)d_in[7];
    const float* l2_w2 = (const float*)d_in[8];
    const float* l2_b2 = (const float*)d_in[9];
    const float* l2_dw = (const float*)d_in[10];
    const float* l3_w1 = (const float*)d_in[11];
    const float* l3_b1 = (const float*)d_in[12];
    const float* l3_w2 = (const float*)d_in[13];
    const float* l3_b2 = (const float*)d_in[14];
    const float* l3_dw = (const float*)d_in[15];
    const float* l4_w1 = (const float*)d_in[16];
    const float* l4_b1 = (const float*)d_in[17];
    const float* l4_w2 = (const float*)d_in[18];
    const float* l4_b2 = (const float*)d_in[19];
    const float* l4_dw = (const float*)d_in[20];
    const float* fc_w  = (const float*)d_in[21];
    const float* fc_b  = (const float*)d_in[22];
    float* outp = (float*)d_out;

    char* bp = (char*)d_ws;
    auto alloc = [&](size_t bytes) {
        char* r = bp;
        bp += (bytes + 255) & ~(size_t)255;
        return (void*)r;
    };
    ushortT* A16 = (ushortT*)alloc(6718464ull * 2); // conv1 out bf16 [18^4][64]
    ushortT* Aw1 = (ushortT*)alloc(200704ull * 2);
    ushortT* X0 = (ushortT*)alloc(419904ull * 2);
    ushortT* Y1 = (ushortT*)alloc(419904ull * 2);
    ushortT* X1 = (ushortT*)alloc(419904ull * 2);
    ushortT* Y2 = (ushortT*)alloc(80000ull * 2);
    ushortT* R2 = (ushortT*)alloc(80000ull * 2);
    ushortT* X2 = (ushortT*)alloc(80000ull * 2);
    ushortT* Y3 = (ushortT*)alloc(20736ull * 2);
    ushortT* R3 = (ushortT*)alloc(20736ull * 2);
    ushortT* X3 = (ushortT*)alloc(20736ull * 2);
    ushortT* Y4 = (ushortT*)alloc(8192ull * 2);
    ushortT* R4 = (ushortT*)alloc(8192ull * 2);
    ushortT* X4 = (ushortT*)alloc(8192ull * 2);
    ushortT* W11 = (ushortT*)alloc(331776ull * 2);
    ushortT* W12 = (ushortT*)alloc(331776ull * 2);
    ushortT* W21 = (ushortT*)alloc(663552ull * 2);
    ushortT* W22 = (ushortT*)alloc(1327104ull * 2);
    ushortT* W31 = (ushortT*)alloc(2654208ull * 2);
    ushortT* W32 = (ushortT*)alloc(5308416ull * 2);
    ushortT* W41 = (ushortT*)alloc(10616832ull * 2);
    ushortT* W42 = (ushortT*)alloc(21233664ull * 2);
    float* P    = (float*)alloc(82944ull * 4);
    ushortT* ZB = (ushortT*)alloc(256);
    if ((size_t)(bp - (char*)d_ws) > ws_size) return; // workspace too small: fail cleanly

    // ---- weight preparation ----
    wprep1<<<784, 256, 0, stream>>>(conv1_w, Aw1);
    wprep<<<192,  256, 0, stream>>>(l1_w1, W11, 64, 64);
    wprep<<<192,  256, 0, stream>>>(l1_w2, W12, 64, 64);
    wprep<<<384,  256, 0, stream>>>(l2_w1, W21, 64, 128);
    wprep<<<384,  256, 0, stream>>>(l2_w2, W22, 128, 128);
    wprep<<<768,  256, 0, stream>>>(l3_w1, W31, 128, 256);
    wprep<<<768,  256, 0, stream>>>(l3_w2, W32, 256, 256);
    wprep<<<1536, 256, 0, stream>>>(l4_w1, W41, 256, 512);
    wprep<<<1536, 256, 0, stream>>>(l4_w2, W42, 512, 512);

    // ---- stem ----
    conv1_mfma3<<<1350, 256, 0, stream>>>(x, Aw1, A16);
    maxpool2<<<(6561 * 16 + 255) / 256, 256, 0, stream>>>(A16, X0, ZB);

    // ---- layer1: 64->64, T=9, s1, identity residual ----
    convmfma<2, 1><<<dim3(411, 1, 1), 256, 0, stream>>>(X0, W11, l1_b1, nullptr, Y1, nullptr,
                                                        ZB, 64, 64, 9, 9, 1, 64);
    convmfma<2, 1><<<dim3(411, 1, 1), 256, 0, stream>>>(Y1, W12, l1_b2, X0, X1, nullptr,
                                                        ZB, 64, 64, 9, 9, 1, 64);

    // ---- layer2: 64->128, 9->5, s2 ----
    dwconv2<<<(80000 + 255) / 256, 256, 0, stream>>>(X1, l2_dw, R2, 64, 128, 9, 5, 80000);
    convmfma<2, 1><<<dim3(40, 2, 1), 256, 0, stream>>>(X1, W21, l2_b1, nullptr, Y2, nullptr,
                                                       ZB, 64, 128, 9, 5, 2, 64);
    convmfma<4, 1><<<dim3(40, 2, 1), 256, 0, stream>>>(Y2, W22, l2_b2, R2, X2, nullptr,
                                                       ZB, 128, 128, 5, 5, 1, 128);

    // ---- layer3: 128->256, 5->3, s2 (ci-split KS=4) ----
    dwconv2<<<(20736 + 255) / 256, 256, 0, stream>>>(X2, l3_dw, R3, 128, 256, 5, 3, 20736);
    convmfma<1, 0><<<dim3(6, 4, 4), 256, 0, stream>>>(X2, W31, nullptr, nullptr, nullptr, P,
                                                      ZB, 128, 256, 5, 3, 2, 32);
    finalize_k<<<(20736 + 255) / 256, 256, 0, stream>>>(P, 4, l3_b1, nullptr, Y3, 256, 81,
                                                        5, 3, 2, 20736);
    convmfma<2, 0><<<dim3(6, 4, 4), 256, 0, stream>>>(Y3, W32, nullptr, nullptr, nullptr, P,
                                                      ZB, 256, 256, 3, 3, 1, 64);
    finalize_k<<<(20736 + 255) / 256, 256, 0, stream>>>(P, 4, l3_b2, R3, X3, 256, 81,
                                                        3, 3, 1, 20736);

    // ---- layer4: 256->512, 3->2, s2 (ci-split KS=8) ----
    dwconv2<<<(8192 + 255) / 256, 256, 0, stream>>>(X3, l4_dw, R4, 256, 512, 3, 2, 8192);
    convmfma<1, 0><<<dim3(1, 8, 8), 256, 0, stream>>>(X3, W41, nullptr, nullptr, nullptr, P,
                                                      ZB, 256, 512, 3, 2, 2, 32);
    finalize_k<<<(8192 + 255) / 256, 256, 0, stream>>>(P, 8, l4_b1, nullptr, Y4, 512, 16,
                                                       3, 2, 2, 8192);
    convmfma<2, 0><<<dim3(1, 8, 8), 256, 0, stream>>>(Y4, W42, nullptr, nullptr, nullptr, P,
                                                      ZB, 512, 512, 2, 2, 1, 64);
    finalize_k<<<(8192 + 255) / 256, 256, 0, stream>>>(P, 8, l4_b2, R4, X4, 512, 16,
                                                       2, 2, 1, 8192);

    // ---- head ----
    avgfc2<<<1, 512, 0, stream>>>(X4, fc_w, fc_b, outp);
}